// Round 1
// baseline (721.402 us; speedup 1.0000x reference)
//
#include <hip/hip_runtime.h>
#include <hip/hip_bf16.h>

#define BB 64
#define NN 64
#define FF 32
#define CH 128
#define ICI 129
#define PIX_PER_B (NN*NN)
#define NPIX (BB*PIX_PER_B)
#define INV63 (1.0f/63.0f)
#define INV3969 (1.0f/3969.0f)
#define LDA (CH+8)

typedef __attribute__((ext_vector_type(8))) __bf16 bfv8;
typedef __attribute__((ext_vector_type(4))) float fv4;

// ---------- weight transform: W'[o][j] for layers 2..4, both branches ----------
__global__ void wprep(const float* w2a, const float* w3a, const float* w4a,
                      const float* w2b, const float* w3b, const float* w4b,
                      __hip_bfloat16* Wp) {
    int bid = blockIdx.x;           // 0..5
    int br = bid / 3, l = bid % 3;
    const float* w = (br == 0) ? (l == 0 ? w2a : (l == 1 ? w3a : w4a))
                               : (l == 0 ? w2b : (l == 1 ? w3b : w4b));
    __hip_bfloat16* dst = Wp + (size_t)(br * 3 + l) * CH * CH;
    for (int idx = threadIdx.x; idx < CH * CH; idx += blockDim.x) {
        int o = idx >> 7, j = idx & 127;
        int c = j & 31, grp = j >> 5;
        float v;
        if (grp == 0)      v =  w[o * ICI + 1 + c];
        else if (grp == 1) v = -w[o * ICI + 33 + c] * INV63;
        else if (grp == 2) v = -w[o * ICI + 65 + c] * INV63;
        else               v =  w[o * ICI + 97 + c] * INV3969;
        dst[idx] = __float2bfloat16(v);
    }
}

// ---------- layer 1: y1 = relu(w1*channel + b1), bf16 [slot][pix][ch] ----------
__global__ void e1(const float* channel, const float* w1a, const float* b1a,
                   const float* w1b, const float* b1b, __hip_bfloat16* y, int br0) {
    int slot = blockIdx.y;
    int br = br0 + slot;
    const float* w1 = br ? w1b : w1a;
    const float* b1 = br ? b1b : b1a;
    int row = blockIdx.x;                       // b*64 + x
    const float* chrow = channel + (size_t)row * NN;
    __hip_bfloat16* dst = y + (size_t)slot * NPIX * CH + (size_t)row * NN * CH;
    __shared__ float w1s[CH], b1s[CH], chs[NN];
    for (int t = threadIdx.x; t < CH; t += blockDim.x) { w1s[t] = w1[t]; b1s[t] = b1[t]; }
    for (int t = threadIdx.x; t < NN; t += blockDim.x) chs[t] = chrow[t];
    __syncthreads();
    for (int idx = threadIdx.x; idx < NN * CH; idx += blockDim.x) {
        int yy = idx >> 7, ch = idx & 127;
        float v = w1s[ch] * chs[yy] + b1s[ch];
        dst[idx] = __float2bfloat16(fmaxf(v, 0.f));
    }
}

// ---------- reductions: rowsum(ch 64..127) over y-dim; colsum(ch 32..63,96..127) over x-dim ----------
__global__ void red(const __hip_bfloat16* y, float* rowsum, float* colsum) {
    int slot = blockIdx.y;
    const __hip_bfloat16* ys = y + (size_t)slot * NPIX * CH;
    int bid = blockIdx.x;
    int t = threadIdx.x;                        // 0..63
    if (bid < BB * NN) {                        // rowsum for (b,x): ch = 64+t
        size_t pixbase = (size_t)bid * NN;
        float acc = 0.f;
        for (int yy = 0; yy < NN; ++yy)
            acc += __bfloat162float(ys[(pixbase + yy) * CH + 64 + t]);
        rowsum[(size_t)slot * BB * NN * 64 + (size_t)bid * 64 + t] = acc;
    } else {                                    // colsum for (b,yc)
        int id = bid - BB * NN;
        int b = id >> 6, yc = id & 63;
        int ch = (t < 32) ? (32 + t) : (64 + t);
        float acc = 0.f;
        size_t base = (size_t)b * PIX_PER_B;
        for (int x = 0; x < NN; ++x)
            acc += __bfloat162float(ys[(base + (size_t)x * NN + yc) * CH + ch]);
        colsum[(size_t)slot * BB * NN * 64 + (size_t)id * 64 + t] = acc;
    }
}

// ---------- bias prep: rowbias[b][x][o], colbias[b][y][o] (fp32, raw weights) ----------
__global__ void pb(const float* wA, const float* wB, const float* bA, const float* bB,
                   const float* rowsum, const float* colsum,
                   float* rowbias, float* colbias, int br0) {
    int slot = blockIdx.y; int br = br0 + slot;
    const float* w  = br ? wB : wA;
    const float* bv = br ? bB : bA;
    const float* rs = rowsum + (size_t)slot * BB * NN * 64;
    const float* cs = colsum + (size_t)slot * BB * NN * 64;
    int bid = blockIdx.x;
    int o = threadIdx.x;                        // 0..127
    __shared__ float tot3[32];
    if (bid < BB * NN) {                        // row blocks (b,x)
        int b = bid >> 6;
        if (o < 32) {
            float s = 0.f;
            for (int xx = 0; xx < NN; ++xx) s += rs[(size_t)(b * NN + xx) * 64 + 32 + o];
            tot3[o] = s;
        }
        __syncthreads();
        const float* rrow = rs + (size_t)bid * 64;
        float acc = bv[o];
        for (int c = 0; c < 32; ++c) {
            acc += w[o * ICI + 65 + c] * rrow[c] * INV63;
            acc += w[o * ICI + 97 + c] * (tot3[c] - rrow[32 + c]) * INV3969;
        }
        rowbias[(size_t)slot * BB * NN * CH + (size_t)bid * CH + o] = acc;
    } else {                                    // col blocks (b,yc)
        int id = bid - BB * NN;
        const float* crow = cs + (size_t)id * 64;
        float acc = 0.f;
        for (int c = 0; c < 32; ++c) {
            acc += w[o * ICI + 33 + c] * crow[c] * INV63;
            acc -= w[o * ICI + 97 + c] * crow[32 + c] * INV3969;
        }
        colbias[(size_t)slot * BB * NN * CH + (size_t)id * CH + o] = acc;
    }
}

// ---------- fused conv+post GEMM (in-place on y): y = relu(W'y + w0*ch + rb + cb) ----------
__global__ __launch_bounds__(256) void gemm(
        __hip_bfloat16* y, const __hip_bfloat16* Wp, int lidx,
        const float* wA, const float* wB,
        const float* rowbias, const float* colbias, const float* channel, int br0) {
    int slot = blockIdx.y; int br = br0 + slot;
    const __hip_bfloat16* Wl = Wp + (size_t)(br * 3 + lidx) * CH * CH;
    const float* wraw = br ? wB : wA;
    __hip_bfloat16* ys = y + (size_t)slot * NPIX * CH;
    int bid = blockIdx.x;                       // b*64 + x
    int b = bid >> 6;
    size_t pixbase = (size_t)bid * NN;

    __shared__ __hip_bfloat16 As[NN * LDA];
    __shared__ __hip_bfloat16 Ws[CH * LDA];
    int tid = threadIdx.x;
    {
        int rowi = tid >> 4, seg = tid & 15;
        #pragma unroll
        for (int it = 0; it < 4; ++it) {        // A: 64 rows x 128 ch
            int row = it * 16 + rowi;
            uint4 v = *reinterpret_cast<const uint4*>(ys + (pixbase + row) * CH + seg * 8);
            *reinterpret_cast<uint4*>(&As[row * LDA + seg * 8]) = v;
        }
        #pragma unroll
        for (int it = 0; it < 8; ++it) {        // W': 128 rows x 128
            int row = it * 16 + rowi;
            uint4 v = *reinterpret_cast<const uint4*>(Wl + (size_t)row * CH + seg * 8);
            *reinterpret_cast<uint4*>(&Ws[row * LDA + seg * 8]) = v;
        }
    }
    __syncthreads();

    int wave = tid >> 6, lane = tid & 63;
    int rowgrp = lane >> 4, l16 = lane & 15;
    fv4 acc[8] = {};
    #pragma unroll
    for (int ks = 0; ks < 4; ++ks) {
        int kofs = ks * 32 + rowgrp * 8;
        bfv8 af = *reinterpret_cast<const bfv8*>(&As[(wave * 16 + l16) * LDA + kofs]);
        #pragma unroll
        for (int oc = 0; oc < 8; ++oc) {
            bfv8 bf = *reinterpret_cast<const bfv8*>(&Ws[(oc * 16 + l16) * LDA + kofs]);
            acc[oc] = __builtin_amdgcn_mfma_f32_16x16x32_bf16(af, bf, acc[oc], 0, 0, 0);
        }
    }
    // epilogue (writes only this block's own pixels -> in-place safe)
    const float* rb = rowbias + (size_t)slot * BB * NN * CH + (size_t)bid * CH;
    const float* cb = colbias + (size_t)slot * BB * NN * CH + (size_t)(b * NN) * CH;
    const float* chrow = channel + (size_t)bid * NN;
    #pragma unroll
    for (int oc = 0; oc < 8; ++oc) {
        int o = oc * 16 + l16;
        float w0 = wraw[o * ICI];
        float rbo = rb[o];
        #pragma unroll
        for (int r = 0; r < 4; ++r) {
            int yy = wave * 16 + rowgrp * 4 + r;
            float v = acc[oc][r] + w0 * chrow[yy] + rbo + cb[(size_t)yy * CH + o];
            ys[(pixbase + yy) * CH + o] = __float2bfloat16(fmaxf(v, 0.f));
        }
    }
}

// ---------- final layer (diag only) ----------
__global__ void fin(const __hip_bfloat16* y4, const float* rowsum, const float* colsum,
                    const float* w5A, const float* w5B, const float* b5A, const float* b5B,
                    const float* channel, float* outbr, int br0) {
    int slot = blockIdx.y; int br = br0 + slot;
    const float* w5 = br ? w5B : w5A;
    float b5 = (br ? b5B : b5A)[0];
    const __hip_bfloat16* ys = y4 + (size_t)slot * NPIX * CH;
    const float* rs = rowsum + (size_t)slot * BB * NN * 64;
    const float* cs = colsum + (size_t)slot * BB * NN * 64;
    int b = blockIdx.x;
    int x = threadIdx.x;                        // 0..63
    __shared__ float tot3[32];
    if (x < 32) {
        float s = 0.f;
        for (int xx = 0; xx < NN; ++xx) s += rs[(size_t)(b * NN + xx) * 64 + 32 + x];
        tot3[x] = s;
    }
    __syncthreads();
    size_t pix = (size_t)b * PIX_PER_B + (size_t)x * NN + x;
    const __hip_bfloat16* yv = ys + pix * CH;
    const float* rrow = rs + (size_t)(b * NN + x) * 64;
    const float* crow = cs + (size_t)(b * NN + x) * 64;
    float acc = b5 + w5[0] * channel[pix];
    for (int c = 0; c < 32; ++c) {
        acc += w5[1 + c]  * __bfloat162float(yv[c]);
        acc += w5[33 + c] * (crow[c] - __bfloat162float(yv[32 + c])) * INV63;
        acc += w5[65 + c] * (rrow[c] - __bfloat162float(yv[64 + c])) * INV63;
        acc += w5[97 + c] * (tot3[c] - rrow[32 + c] - crow[32 + c] + __bfloat162float(yv[96 + c])) * INV3969;
    }
    outbr[(size_t)br * BB * NN + (size_t)b * NN + x] = acc;
}

// ---------- combine ----------
__global__ void combine(const float* outbr, const float* u, float* out) {
    int b = blockIdx.x, x = threadIdx.x;
    float av = outbr[b * NN + x] - 2.0f;
    float bv = outbr[BB * NN + b * NN + x] + 4.0f;
    bv = fmaxf(bv, 1e-8f);
    float high = av + bv;
    float action = av + bv * u[b * NN + x];
    float s = logf(bv);
    for (int m = 32; m; m >>= 1) s += __shfl_xor(s, m, 64);
    out[b * NN + x] = action;                   // action  [0,4096)
    if (x == 0) out[BB * NN + b] = s;           // entropy [4096,4160)
    out[BB * NN + BB + b * NN + x] = av;        // a       [4160,8256)
    out[2 * BB * NN + BB + b * NN + x] = high;  // high    [8256,12352)
}

extern "C" void kernel_launch(void* const* d_in, const int* in_sizes, int n_in,
                              void* d_out, int out_size, void* d_ws, size_t ws_size,
                              hipStream_t stream) {
    const float* channel = (const float*)d_in[0];
    const float* u = (const float*)d_in[1];
    const float* w[2][5]; const float* bv[2][5];
    for (int br = 0; br < 2; ++br)
        for (int l = 0; l < 5; ++l) {
            w[br][l]  = (const float*)d_in[2 + br * 10 + l * 2];
            bv[br][l] = (const float*)d_in[3 + br * 10 + l * 2];
        }

    char* p = (char*)d_ws;
    auto alloc = [&](size_t bytes) { char* r = p; p += (bytes + 255) & ~255ull; return r; };
    size_t ybytes   = (size_t)NPIX * CH * 2;                      // 67.1 MB / slot
    size_t per_slot = ybytes + 2 * (size_t)BB * NN * 64 * 4 + 2 * (size_t)BB * NN * CH * 4;
    size_t fixed    = 2 * 3 * CH * CH * 2 + 2 * BB * NN * 4 + 8192;
    int nslot = (ws_size >= fixed + 2 * per_slot) ? 2 : 1;

    __hip_bfloat16* Wp = (__hip_bfloat16*)alloc(2 * 3 * CH * CH * 2);
    float* outbr = (float*)alloc(2 * BB * NN * 4);
    __hip_bfloat16* yb = (__hip_bfloat16*)alloc((size_t)nslot * ybytes);
    float* rowsum  = (float*)alloc((size_t)nslot * BB * NN * 64 * 4);
    float* colsum  = (float*)alloc((size_t)nslot * BB * NN * 64 * 4);
    float* rowbias = (float*)alloc((size_t)nslot * BB * NN * CH * 4);
    float* colbias = (float*)alloc((size_t)nslot * BB * NN * CH * 4);

    wprep<<<6, 256, 0, stream>>>(w[0][1], w[0][2], w[0][3], w[1][1], w[1][2], w[1][3], Wp);

    int npass = (nslot == 2) ? 1 : 2;
    for (int ps = 0; ps < npass; ++ps) {
        int br0 = (nslot == 2) ? 0 : ps;
        e1<<<dim3(BB * NN, nslot), 256, 0, stream>>>(channel, w[0][0], bv[0][0], w[1][0], bv[1][0], yb, br0);
        for (int l = 0; l < 3; ++l) {           // layers 2..4
            red<<<dim3(2 * BB * NN, nslot), 64, 0, stream>>>(yb, rowsum, colsum);
            pb<<<dim3(2 * BB * NN, nslot), 128, 0, stream>>>(w[0][l + 1], w[1][l + 1], bv[0][l + 1], bv[1][l + 1],
                                                             rowsum, colsum, rowbias, colbias, br0);
            gemm<<<dim3(BB * NN, nslot), 256, 0, stream>>>(yb, Wp, l, w[0][l + 1], w[1][l + 1],
                                                           rowbias, colbias, channel, br0);
        }
        red<<<dim3(2 * BB * NN, nslot), 64, 0, stream>>>(yb, rowsum, colsum);
        fin<<<dim3(BB, nslot), 64, 0, stream>>>(yb, rowsum, colsum, w[0][4], w[1][4], bv[0][4], bv[1][4],
                                                channel, outbr, br0);
    }
    combine<<<BB, 64, 0, stream>>>(outbr, u, (float*)d_out);
}